// Round 1
// baseline (583.531 us; speedup 1.0000x reference)
//
#include <hip/hip_runtime.h>

#define BB 512
#define LL 1024
#define DD 16
#define HH 64
#define CH 16    // timesteps per chunk
#define YP 68    // sh_yp row stride (floats), padded: 2-way bank alias only

typedef _Float16 half2_t __attribute__((ext_vector_type(2)));

__device__ __forceinline__ half2_t h2(unsigned u) {
    return __builtin_bit_cast(half2_t, u);
}
__device__ __forceinline__ unsigned pk2_(float a, float b) {
    unsigned ha = (unsigned)__builtin_bit_cast(unsigned short, (_Float16)a);
    unsigned hb = (unsigned)__builtin_bit_cast(unsigned short, (_Float16)b);
    return ha | (hb << 16);
}
__device__ __forceinline__ float flo_(float a) {   // a - f16(a)
    return a - (float)((_Float16)a);
}
__device__ __forceinline__ float sigmoidf_(float x) {
    return __builtin_amdgcn_rcpf(1.0f + __expf(-x));
}
__device__ __forceinline__ float tanhf_(float x) {
    x = fminf(fmaxf(x, -15.0f), 15.0f);
    float e = __expf(2.0f * x);
    return (e - 1.0f) * __builtin_amdgcn_rcpf(e + 1.0f);
}
#define DOT2(w, h, acc) __builtin_amdgcn_fdot2((w), (h), (acc), false)

// R13: lane^1 exchange via DPP quad_perm [1,0,3,2] (VALU, ~4cyc) instead of
// __shfl_xor (ds_bpermute -> forced lgkmcnt drain of the prefetch queue on
// the serial path every step). Packs (hbar[2m],hbar[2m+1]) for even lanes.
__device__ __forceinline__ unsigned pk_pair(float a) {
    int ai = __builtin_bit_cast(int, a);
    int bi = __builtin_amdgcn_update_dpp(ai, ai, 0xB1, 0xF, 0xF, false);
    float b = __builtin_bit_cast(float, bi);
    return __builtin_bit_cast(unsigned, __builtin_amdgcn_cvt_pkrtz(a, b));
}

// Ban the AGPR file (see R9): keeps all long-lived arrays in arch VGPRs.
#define AGPR_CLOBBER() asm volatile("" ::: \
    "a0","a1","a2","a3","a4","a5","a6","a7","a8","a9","a10","a11","a12","a13","a14","a15", \
    "a16","a17","a18","a19","a20","a21","a22","a23","a24","a25","a26","a27","a28","a29","a30","a31", \
    "a32","a33","a34","a35","a36","a37","a38","a39","a40","a41","a42","a43","a44","a45","a46","a47", \
    "a48","a49","a50","a51","a52","a53","a54","a55","a56","a57","a58","a59","a60","a61","a62","a63", \
    "a64","a65","a66","a67","a68","a69","a70","a71","a72","a73","a74","a75","a76","a77","a78","a79", \
    "a80","a81","a82","a83","a84","a85","a86","a87","a88","a89","a90","a91","a92","a93","a94","a95", \
    "a96","a97","a98","a99","a100","a101","a102","a103","a104","a105","a106","a107","a108","a109","a110","a111", \
    "a112","a113","a114","a115","a116","a117","a118","a119","a120","a121","a122","a123","a124","a125","a126","a127", \
    "a128","a129","a130","a131","a132","a133","a134","a135","a136","a137","a138","a139","a140","a141","a142","a143", \
    "a144","a145","a146","a147","a148","a149","a150","a151","a152","a153","a154","a155","a156","a157","a158","a159", \
    "a160","a161","a162","a163","a164","a165","a166","a167","a168","a169","a170","a171","a172","a173","a174","a175", \
    "a176","a177","a178","a179","a180","a181","a182","a183","a184","a185","a186","a187","a188","a189","a190","a191", \
    "a192","a193","a194","a195","a196","a197","a198","a199","a200","a201","a202","a203","a204","a205","a206","a207", \
    "a208","a209","a210","a211","a212","a213","a214","a215","a216","a217","a218","a219","a220","a221","a222","a223", \
    "a224","a225","a226","a227","a228","a229","a230","a231","a232","a233","a234","a235","a236","a237","a238","a239", \
    "a240","a241","a242","a243","a244","a245","a246","a247","a248","a249","a250","a251","a252","a253","a254","a255")

// One wave per (dir, batch): 1024 blocks x 64 threads, zero barriers, no MFMA.
// R13 changes vs R12 (586.1 us):
//  - shfl_xor -> DPP quad_perm: h-pack is pure VALU, no per-step LDS drain.
//  - pack moved to step TAIL (uses prefetched next-step decay), so next
//    step's readlane chain starts immediately off registers.
//  - 9 accumulation chains (3 x-path + 6 h-path) instead of 3: same-chain
//    issue gap >= dot2 dependent latency.
//  - next chunk's x/dt global loads issued at current chunk start
//    (register double-buffer): HBM latency off the chunk-boundary path.
__global__ __launch_bounds__(64, 1) void brios_main(
    const float* __restrict__ x, const float* __restrict__ dt,
    const float* __restrict__ f_Wih, const float* __restrict__ f_Whh,
    const float* __restrict__ f_bih, const float* __restrict__ f_bhh,
    const float* __restrict__ f_gamma, const float* __restrict__ f_Wout,
    const float* __restrict__ f_bout,
    const float* __restrict__ b_Wih, const float* __restrict__ b_Whh,
    const float* __restrict__ b_bih, const float* __restrict__ b_bhh,
    const float* __restrict__ b_gamma, const float* __restrict__ b_Wout,
    const float* __restrict__ b_bout,
    float* __restrict__ out)
{
    const int lane = threadIdx.x;
    const int dir  = blockIdx.x >> 9;
    const int b    = blockIdx.x & 511;

    const float* Wih  = dir ? b_Wih  : f_Wih;
    const float* Whh  = dir ? b_Whh  : f_Whh;
    const float* bih  = dir ? b_bih  : f_bih;
    const float* bhh  = dir ? b_bhh  : f_bhh;
    const float* Wout = dir ? b_Wout : f_Wout;
    float gam = dir ? b_gamma[0] : f_gamma[0];
    gam = fminf(fmaxf(gam, 1e-4f), 10.0f);
    const float bo = dir ? b_bout[0] : f_bout[0];

    // ---- Wih: f16 k-pairs, 24 regs
    unsigned wxr[8], wxz[8], wxn[8];
#pragma unroll
    for (int p = 0; p < 8; ++p) {
        const float* r0 = Wih + (size_t)(      lane) * DD + 2 * p;
        const float* r1 = Wih + (size_t)( 64 + lane) * DD + 2 * p;
        const float* r2 = Wih + (size_t)(128 + lane) * DD + 2 * p;
        wxr[p] = pk2_(r0[0], r0[1]);
        wxz[p] = pk2_(r1[0], r1[1]);
        wxn[p] = pk2_(r2[0], r2[1]);
    }
    // ---- Whh: f16 k-pairs, lane j owns rows j, 64+j, 128+j (96 VGPRs)
    unsigned whr[32], whz[32], whn[32];
#pragma unroll
    for (int p = 0; p < 32; ++p) {
        const float* r0 = Whh + (size_t)(      lane) * HH + 2 * p;
        const float* r1 = Whh + (size_t)( 64 + lane) * HH + 2 * p;
        const float* r2 = Whh + (size_t)(128 + lane) * HH + 2 * p;
        whr[p] = pk2_(r0[0], r0[1]);
        whz[p] = pk2_(r1[0], r1[1]);
        whn[p] = pk2_(r2[0], r2[1]);
    }
    const float br  = bih[lane]      + bhh[lane];
    const float bz  = bih[64 + lane] + bhh[64 + lane];
    const float bni = bih[128 + lane];
    const float bnh = bhh[128 + lane];
    const float wo  = Wout[lane];

    __shared__ alignas(16) unsigned sh_xh[CH][8];   // x hi-f16 pairs
    __shared__ alignas(16) unsigned sh_xl[CH][8];   // x lo-f16 pairs
    __shared__ alignas(16) float sh_yp[CH][YP];     // per-lane y products
    __shared__ float sh_dcy[CH];

    float h_reg = 0.0f;      // lane j holds h[j], fp32
    float* yd = out + (size_t)(1 + dir) * (BB * LL);

    const int tq = lane >> 2, d4 = lane & 3;
    auto xaddr = [&](int c) __attribute__((always_inline)) {
        int sbase = c * CH;
        int t_low = dir ? (LL - CH - sbase) : sbase;
        return x + ((size_t)b * LL + t_low + tq) * DD + d4 * 4;
    };
    auto dtaddr = [&](int c) __attribute__((always_inline)) {
        int si = c * CH + lane;                 // only lanes < CH use this
        int t = dir ? (LL - 1 - si) : si;
        return dt + (size_t)b * LL + t;
    };

    // one GRU step. Consumes (xh,xl) regs + (hbar,hpku); prefetches step
    // `inx`'s x into (pxh,pxl); at the TAIL produces next step's
    // (hbar,hpku) from the prefetched decay — pure-VALU serial path.
    auto step = [&](int i, int inx,
                    unsigned* xh, unsigned* xl,
                    float hbar, unsigned hpku,
                    unsigned* pxh, unsigned* pxl,
                    float* nhb, unsigned* npu)
                    __attribute__((always_inline)) {
        *(uint4*)&pxh[0] = *(const uint4*)&sh_xh[inx][0];
        *(uint4*)&pxh[4] = *(const uint4*)&sh_xh[inx][4];
        *(uint4*)&pxl[0] = *(const uint4*)&sh_xl[inx][0];
        *(uint4*)&pxl[4] = *(const uint4*)&sh_xl[inx][4];
        float dn = sh_dcy[inx];                 // decay for step i+1

        // x-path: 3 chains, h-independent
        float ra = br, za = bz, gn = bni;
#pragma unroll
        for (int p = 0; p < 8; ++p) {
            half2_t hp = h2(xh[p]);
            ra = DOT2(h2(wxr[p]), hp, ra);
            za = DOT2(h2(wxz[p]), hp, za);
            gn = DOT2(h2(wxn[p]), hp, gn);
        }
#pragma unroll
        for (int p = 0; p < 8; ++p) {
            half2_t lp = h2(xl[p]);
            ra = DOT2(h2(wxr[p]), lp, ra);
            za = DOT2(h2(wxz[p]), lp, za);
            gn = DOT2(h2(wxn[p]), lp, gn);
        }
        // h-path: 6 chains (even/odd k-pair), merged before activations
        float rh0 = 0.f, zh0 = 0.f, nh0 = 0.f;
        float rh1 = 0.f, zh1 = 0.f, nh1 = 0.f;
#pragma unroll
        for (int p = 0; p < 32; p += 2) {
            unsigned s0 = (unsigned)__builtin_amdgcn_readlane((int)hpku, 2 * p);
            unsigned s1 = (unsigned)__builtin_amdgcn_readlane((int)hpku, 2 * p + 2);
            half2_t h0 = h2(s0), h1 = h2(s1);
            rh0 = DOT2(h2(whr[p]),     h0, rh0);
            zh0 = DOT2(h2(whz[p]),     h0, zh0);
            nh0 = DOT2(h2(whn[p]),     h0, nh0);
            rh1 = DOT2(h2(whr[p + 1]), h1, rh1);
            zh1 = DOT2(h2(whz[p + 1]), h1, zh1);
            nh1 = DOT2(h2(whn[p + 1]), h1, nh1);
        }
        float r = sigmoidf_(ra + (rh0 + rh1));
        float z = sigmoidf_(za + (zh0 + zh1));
        float n = tanhf_(gn + r * ((nh0 + nh1) + bnh));
        float hnew = n + z * (hbar - n);
        h_reg = hnew;
        sh_yp[i][lane] = wo * hnew;             // off-chain y product

        float hbn = dn * hnew;                  // next step's hbar
        *nhb = hbn;
        *npu = pk_pair(hbn);                    // DPP + cvt_pkrtz, no LDS
    };

    // ---- chunk 0's x/dt into registers (double-buffered across chunks)
    float4 vx = *(const float4*)xaddr(0);
    float dtv = (lane < CH) ? *dtaddr(0) : 0.0f;

#pragma unroll 1
    for (int c = 0; c < LL / CH; ++c) {
        AGPR_CLOBBER();      // no value may live in an AGPR across a chunk

        const int sbase = c * CH;

        // ---- stage x (from prefetched regs) as f16 hi/lo pairs + decay
        {
            int sl = dir ? (CH - 1 - tq) : tq;
            uint2 hp, lp;
            hp.x = pk2_(vx.x, vx.y);
            hp.y = pk2_(vx.z, vx.w);
            lp.x = pk2_(flo_(vx.x), flo_(vx.y));
            lp.y = pk2_(flo_(vx.z), flo_(vx.w));
            *(uint2*)&sh_xh[sl][d4 * 2] = hp;
            *(uint2*)&sh_xl[sl][d4 * 2] = lp;
            if (lane < CH) {
                float dv = fminf(fmaxf(dtv, 0.0f), 1e6f);
                sh_dcy[lane] = __expf(-gam * dv);
            }
        }
        // ---- issue NEXT chunk's global loads now; consumed next chunk
        if (c + 1 < LL / CH) {
            vx = *(const float4*)xaddr(c + 1);
            if (lane < CH) dtv = *dtaddr(c + 1);
        }
        // single wave: in-order DS pipe + compiler waitcnts, no barrier

        // ---- preload step 0 regs + initial h-pack for this chunk
        unsigned xAh[8], xAl[8], xBh[8], xBl[8];
        *(uint4*)&xAh[0] = *(const uint4*)&sh_xh[0][0];
        *(uint4*)&xAh[4] = *(const uint4*)&sh_xh[0][4];
        *(uint4*)&xAl[0] = *(const uint4*)&sh_xl[0][0];
        *(uint4*)&xAl[4] = *(const uint4*)&sh_xl[0][4];
        float    hb = sh_dcy[0] * h_reg;
        unsigned pu = pk_pair(hb);

        // ---- recurrent steps, ping-pong prefetch (manual 2-unroll)
#pragma unroll 1
        for (int i = 0; i < CH; i += 2) {
            step(i,     i + 1,                        xAh, xAl, hb, pu, xBh, xBl, &hb, &pu);
            step(i + 1, (i + 2 < CH) ? i + 2 : i + 1, xBh, xBl, hb, pu, xAh, xAl, &hb, &pu);
        }

        // ---- y: lanes 0..15 reduce their step's 64 products, store coalesced
        if (lane < CH) {
            float4 s4 = {0.f, 0.f, 0.f, 0.f};
            const float* rowp = &sh_yp[lane][0];
#pragma unroll
            for (int q = 0; q < 16; ++q) {
                float4 v = *(const float4*)(rowp + q * 4);
                s4.x += v.x; s4.y += v.y; s4.z += v.z; s4.w += v.w;
            }
            float s = (s4.x + s4.y) + (s4.z + s4.w);
            int si = sbase + lane;
            int t = dir ? (LL - 1 - si) : si;
            yd[(size_t)b * LL + t] = s + bo;
        }
    }
}

__global__ __launch_bounds__(256) void brios_avg(float* __restrict__ out)
{
    int i = blockIdx.x * blockDim.x + threadIdx.x;
    const int n4 = (BB * LL) / 4;
    if (i < n4) {
        const float4* yf = (const float4*)(out + (size_t)BB * LL);
        const float4* yb = (const float4*)(out + (size_t)2 * BB * LL);
        float4 a = yf[i], b2 = yb[i];
        float4 r;
        r.x = 0.5f * (a.x + b2.x);
        r.y = 0.5f * (a.y + b2.y);
        r.z = 0.5f * (a.z + b2.z);
        r.w = 0.5f * (a.w + b2.w);
        ((float4*)out)[i] = r;
    }
}

extern "C" void kernel_launch(void* const* d_in, const int* in_sizes, int n_in,
                              void* d_out, int out_size, void* d_ws, size_t ws_size,
                              hipStream_t stream) {
    const float* x       = (const float*)d_in[0];
    const float* dt      = (const float*)d_in[1];
    const float* f_Wih   = (const float*)d_in[2];
    const float* f_Whh   = (const float*)d_in[3];
    const float* f_bih   = (const float*)d_in[4];
    const float* f_bhh   = (const float*)d_in[5];
    const float* f_gamma = (const float*)d_in[6];
    const float* f_Wout  = (const float*)d_in[7];
    const float* f_bout  = (const float*)d_in[8];
    const float* b_Wih   = (const float*)d_in[9];
    const float* b_Whh   = (const float*)d_in[10];
    const float* b_bih   = (const float*)d_in[11];
    const float* b_bhh   = (const float*)d_in[12];
    const float* b_gamma = (const float*)d_in[13];
    const float* b_Wout  = (const float*)d_in[14];
    const float* b_bout  = (const float*)d_in[15];
    float* out = (float*)d_out;

    brios_main<<<1024, 64, 0, stream>>>(x, dt,
        f_Wih, f_Whh, f_bih, f_bhh, f_gamma, f_Wout, f_bout,
        b_Wih, b_Whh, b_bih, b_bhh, b_gamma, b_Wout, b_bout, out);

    const int n4 = (BB * LL) / 4;
    brios_avg<<<(n4 + 255) / 256, 256, 0, stream>>>(out);
}

// Round 2
// 568.121 us; speedup vs baseline: 1.0271x; 1.0271x over previous
//
#include <hip/hip_runtime.h>

#define BB 512
#define LL 1024
#define DD 16
#define HH 64
#define CH 16     // timesteps per chunk
#define NB 16     // batches per block (MFMA N)

typedef _Float16 half8 __attribute__((ext_vector_type(8)));
typedef float    f32x4 __attribute__((ext_vector_type(4)));

__device__ __forceinline__ unsigned pk2_(float a, float b) {
    unsigned ha = (unsigned)__builtin_bit_cast(unsigned short, (_Float16)a);
    unsigned hb = (unsigned)__builtin_bit_cast(unsigned short, (_Float16)b);
    return ha | (hb << 16);
}
__device__ __forceinline__ unsigned pkrtz_(float a, float b) {
    return __builtin_bit_cast(unsigned, __builtin_amdgcn_cvt_pkrtz(a, b));
}
__device__ __forceinline__ float flo_(float a) {   // a - f16(a)
    return a - (float)((_Float16)a);
}
__device__ __forceinline__ float sigmoidf_(float x) {
    return __builtin_amdgcn_rcpf(1.0f + __expf(-x));
}
__device__ __forceinline__ float tanhf_(float x) {
    x = fminf(fmaxf(x, -15.0f), 15.0f);
    float e = __expf(2.0f * x);
    return (e - 1.0f) * __builtin_amdgcn_rcpf(e + 1.0f);
}
#define MFMA16(a, b, c) __builtin_amdgcn_mfma_f32_16x16x32_f16((a), (b), (c), 0, 0, 0)

// LDS strides (elements). All chosen so b128 accesses are 16B-aligned and the
// per-c stride is an ODD multiple of 16B -> bank-quad spread, <=2-way conflict.
#define XST 40    // xh: per-(t,c) stride in f16 (32 payload + 8 pad = 80B, 80/16=5 odd)
#define HST 72    // hb: per-c stride in f16   (64 payload + 8 pad = 144B, 144/16=9 odd)
#define YST 65    // ya: per-(t,w) stride in f32 (4*65=260 dw, %32=4 -> 2-way)

// R14: MFMA-batched restructure. 64 blocks (2 dir x 32 batch-groups) x 256
// threads. Wave w owns gate rows 16w..16w+15 of each of r/z/n (all 3 gates
// same h-rows -> activations + h_new wave-local). Per step per wave:
//   3 x-MFMAs (K=32: x_hi | x_lo stacked, same Wih weights both halves,
//              bias folded into C-init)
// + 6 h-MFMAs (K=64 as 2xK32 on hbar from LDS)
// -> 9 v_mfma_f32_16x16x32_f16 replace the old per-batch dot2 storm.
// hbar broadcast: double-buffered LDS (B-frag layout), ONE barrier/step.
__global__ __launch_bounds__(256, 1) void brios_main(
    const float* __restrict__ x, const float* __restrict__ dt,
    const float* __restrict__ f_Wih, const float* __restrict__ f_Whh,
    const float* __restrict__ f_bih, const float* __restrict__ f_bhh,
    const float* __restrict__ f_gamma, const float* __restrict__ f_Wout,
    const float* __restrict__ f_bout,
    const float* __restrict__ b_Wih, const float* __restrict__ b_Whh,
    const float* __restrict__ b_bih, const float* __restrict__ b_bhh,
    const float* __restrict__ b_gamma, const float* __restrict__ b_Wout,
    const float* __restrict__ b_bout,
    float* __restrict__ out)
{
    const int tid  = threadIdx.x;
    const int w    = tid >> 6;          // wave id 0..3
    const int lane = tid & 63;
    const int lr   = lane & 15;         // A row-in-tile / B,C column (batch)
    const int lg   = lane >> 4;         // k-octet group / C row-quad

    const int dir = blockIdx.x >> 5;    // 2 dirs x 32 groups
    const int bg  = blockIdx.x & 31;

    const float* Wih  = dir ? b_Wih  : f_Wih;
    const float* Whh  = dir ? b_Whh  : f_Whh;
    const float* bih  = dir ? b_bih  : f_bih;
    const float* bhh  = dir ? b_bhh  : f_bhh;
    const float* Wout = dir ? b_Wout : f_Wout;
    float gam = dir ? b_gamma[0] : f_gamma[0];
    gam = fminf(fmaxf(gam, 1e-4f), 10.0f);
    const float bo = dir ? b_bout[0] : f_bout[0];

    // ---- A fragments (weights), f16. Layout: row = lr, k = 8*lg + j.
    const int arow = 16 * w + lr;       // row within each 64-row gate block
    half8 AhR[2], AhZ[2], AhN[2];
#pragma unroll
    for (int kt = 0; kt < 2; ++kt)
#pragma unroll
        for (int j = 0; j < 8; ++j) {
            int k = kt * 32 + lg * 8 + j;
            AhR[kt][j] = (_Float16)Whh[(size_t)(arow      ) * HH + k];
            AhZ[kt][j] = (_Float16)Whh[(size_t)(arow +  64) * HH + k];
            AhN[kt][j] = (_Float16)Whh[(size_t)(arow + 128) * HH + k];
        }
    // x-side: K=32 where k<16 multiplies x_hi, k>=16 multiplies x_lo with the
    // SAME Wih column -> W*(x_hi + x_lo) = W*x at ~f32 input precision.
    half8 AxR, AxZ, AxN;
#pragma unroll
    for (int j = 0; j < 8; ++j) {
        int k = (lg * 8 + j) & 15;
        AxR[j] = (_Float16)Wih[(size_t)(arow      ) * DD + k];
        AxZ[j] = (_Float16)Wih[(size_t)(arow +  64) * DD + k];
        AxN[j] = (_Float16)Wih[(size_t)(arow + 128) * DD + k];
    }

    // ---- per-lane bias / wout (C layout: col=lr, rows rrow..rrow+3)
    const int rrow = 16 * w + 4 * lg;
    f32x4 bR, bZ, bNX, bNH;
    float wo4[4];
#pragma unroll
    for (int j = 0; j < 4; ++j) {
        bR[j]  = bih[rrow + j]       + bhh[rrow + j];
        bZ[j]  = bih[64 + rrow + j]  + bhh[64 + rrow + j];
        bNX[j] = bih[128 + rrow + j];
        bNH[j] = bhh[128 + rrow + j];
        wo4[j] = Wout[rrow + j];
    }

    __shared__ alignas(16) _Float16 xh[CH][NB][XST];   // x B-frags (hi|lo), per t
    __shared__ alignas(16) _Float16 hb[2][NB][HST];    // hbar B-frags, dbuf
    __shared__ float dcy[CH + 1][NB];                  // decay per (t, batch)
    __shared__ float ya[CH][4][YST];                   // per-wave y partials

    // ---- init hbar(0) = 0 (every wave covers its own k rows)
    *(uint2*)&hb[0][lr][rrow] = make_uint2(0u, 0u);
    f32x4 hb4 = {0.f, 0.f, 0.f, 0.f};                  // own rows' hbar, f32
    __syncthreads();

    float* yd = out + (size_t)(1 + dir) * (BB * LL);
    const int tS = tid >> 4, cS = tid & 15;            // staging coords
    const size_t bB = (size_t)bg * NB;                 // first batch of block

#pragma unroll 1
    for (int c0 = 0; c0 < LL / CH; ++c0) {
        const int s0 = c0 * CH;

        // ---- stage x (hi/lo f16) and decay for this chunk
        {
            int s  = s0 + tS;
            int tt = dir ? (LL - 1 - s) : s;
            const float* xp = x + ((bB + cS) * LL + tt) * DD;
            float vv[16];
            *(float4*)(vv + 0)  = *(const float4*)(xp + 0);
            *(float4*)(vv + 4)  = *(const float4*)(xp + 4);
            *(float4*)(vv + 8)  = *(const float4*)(xp + 8);
            *(float4*)(vv + 12) = *(const float4*)(xp + 12);
            unsigned uh[8], ul[8];
#pragma unroll
            for (int d = 0; d < 8; ++d) {
                float a = vv[2 * d], b2 = vv[2 * d + 1];
                uh[d] = pk2_(a, b2);
                ul[d] = pk2_(flo_(a), flo_(b2));
            }
            *(uint4*)&xh[tS][cS][0]  = make_uint4(uh[0], uh[1], uh[2], uh[3]);
            *(uint4*)&xh[tS][cS][8]  = make_uint4(uh[4], uh[5], uh[6], uh[7]);
            *(uint4*)&xh[tS][cS][16] = make_uint4(ul[0], ul[1], ul[2], ul[3]);
            *(uint4*)&xh[tS][cS][24] = make_uint4(ul[4], ul[5], ul[6], ul[7]);

            float dv = dt[(bB + cS) * LL + tt];
            dv = fminf(fmaxf(dv, 0.0f), 1e6f);
            dcy[tS][cS] = __expf(-gam * dv);
            if (tid < NB) {                    // one-past-chunk decay
                int s2 = s0 + CH;
                float d = 0.0f;
                if (s2 < LL) {
                    int t2 = dir ? (LL - 1 - s2) : s2;
                    float dv2 = dt[(bB + tid) * LL + t2];
                    dv2 = fminf(fmaxf(dv2, 0.0f), 1e6f);
                    d = __expf(-gam * dv2);
                }
                dcy[CH][tid] = d;
            }
        }
        __syncthreads();

        // ---- recurrent steps
#pragma unroll 1
        for (int lt = 0; lt < CH; ++lt) {
            const int s  = s0 + lt;
            const int pp = s & 1;

            // B frags: x first (x-MFMAs can start at lgkmcnt(2))
            half8 Bx  = *(const half8*)&xh[lt][lr][lg * 8];
            half8 Bh0 = *(const half8*)&hb[pp][lr][lg * 8];
            half8 Bh1 = *(const half8*)&hb[pp][lr][32 + lg * 8];
            float dnx = dcy[lt + 1][lr];

            f32x4 aR  = MFMA16(AxR, Bx, bR);
            f32x4 aZ  = MFMA16(AxZ, Bx, bZ);
            f32x4 aNX = MFMA16(AxN, Bx, bNX);
            f32x4 aNH = MFMA16(AhN[0], Bh0, bNH);
            aR  = MFMA16(AhR[0], Bh0, aR);
            aZ  = MFMA16(AhZ[0], Bh0, aZ);
            aNH = MFMA16(AhN[1], Bh1, aNH);
            aR  = MFMA16(AhR[1], Bh1, aR);
            aZ  = MFMA16(AhZ[1], Bh1, aZ);

            f32x4 hnew;
#pragma unroll
            for (int j = 0; j < 4; ++j) {
                float r  = sigmoidf_(aR[j]);
                float zz = sigmoidf_(aZ[j]);
                float n  = tanhf_(aNX[j] + r * aNH[j]);
                hnew[j] = n + zz * (hb4[j] - n);
            }

            // critical tail: next hbar -> pack -> LDS (other buffer)
            f32x4 hbn;
#pragma unroll
            for (int j = 0; j < 4; ++j) hbn[j] = hnew[j] * dnx;
            unsigned p0 = pkrtz_(hbn[0], hbn[1]);
            unsigned p1 = pkrtz_(hbn[2], hbn[3]);
            *(uint2*)&hb[pp ^ 1][lr][rrow] = make_uint2(p0, p1);
            hb4 = hbn;

            // y partial (off the recurrence chain)
            float sy = wo4[0] * hnew[0] + wo4[1] * hnew[1]
                     + wo4[2] * hnew[2] + wo4[3] * hnew[3];
            ya[lt][w][lane] = sy;

            __syncthreads();
        }

        // ---- y: reduce 16 partials per (t, batch), store
        {
            int lt2 = tid & 15, c2 = tid >> 4;
            float sacc = 0.0f;
#pragma unroll
            for (int w2 = 0; w2 < 4; ++w2)
#pragma unroll
                for (int g = 0; g < 4; ++g)
                    sacc += ya[lt2][w2][g * 16 + c2];
            int s  = s0 + lt2;
            int tt = dir ? (LL - 1 - s) : s;
            yd[(bB + c2) * LL + tt] = sacc + bo;
        }
        // no barrier needed: next staging touches xh/dcy only, and the
        // staging barrier gates the next steps' ya writes.
    }
}

__global__ __launch_bounds__(256) void brios_avg(float* __restrict__ out)
{
    int i = blockIdx.x * blockDim.x + threadIdx.x;
    const int n4 = (BB * LL) / 4;
    if (i < n4) {
        const float4* yf = (const float4*)(out + (size_t)BB * LL);
        const float4* yb = (const float4*)(out + (size_t)2 * BB * LL);
        float4 a = yf[i], b2 = yb[i];
        float4 r;
        r.x = 0.5f * (a.x + b2.x);
        r.y = 0.5f * (a.y + b2.y);
        r.z = 0.5f * (a.z + b2.z);
        r.w = 0.5f * (a.w + b2.w);
        ((float4*)out)[i] = r;
    }
}

extern "C" void kernel_launch(void* const* d_in, const int* in_sizes, int n_in,
                              void* d_out, int out_size, void* d_ws, size_t ws_size,
                              hipStream_t stream) {
    const float* x       = (const float*)d_in[0];
    const float* dt      = (const float*)d_in[1];
    const float* f_Wih   = (const float*)d_in[2];
    const float* f_Whh   = (const float*)d_in[3];
    const float* f_bih   = (const float*)d_in[4];
    const float* f_bhh   = (const float*)d_in[5];
    const float* f_gamma = (const float*)d_in[6];
    const float* f_Wout  = (const float*)d_in[7];
    const float* f_bout  = (const float*)d_in[8];
    const float* b_Wih   = (const float*)d_in[9];
    const float* b_Whh   = (const float*)d_in[10];
    const float* b_bih   = (const float*)d_in[11];
    const float* b_bhh   = (const float*)d_in[12];
    const float* b_gamma = (const float*)d_in[13];
    const float* b_Wout  = (const float*)d_in[14];
    const float* b_bout  = (const float*)d_in[15];
    float* out = (float*)d_out;

    brios_main<<<64, 256, 0, stream>>>(x, dt,
        f_Wih, f_Whh, f_bih, f_bhh, f_gamma, f_Wout, f_bout,
        b_Wih, b_Whh, b_bih, b_bhh, b_gamma, b_Wout, b_bout, out);

    const int n4 = (BB * LL) / 4;
    brios_avg<<<(n4 + 255) / 256, 256, 0, stream>>>(out);
}

// Round 4
// 534.016 us; speedup vs baseline: 1.0927x; 1.0639x over previous
//
#include <hip/hip_runtime.h>

#define BB 512
#define LL 1024
#define DD 16
#define HH 64
#define CH 16     // timesteps per chunk
#define NB 16     // batches per block (MFMA N)

typedef _Float16 half8 __attribute__((ext_vector_type(8)));
typedef float    f32x4 __attribute__((ext_vector_type(4)));

__device__ __forceinline__ unsigned pk2_(float a, float b) {
    unsigned ha = (unsigned)__builtin_bit_cast(unsigned short, (_Float16)a);
    unsigned hb = (unsigned)__builtin_bit_cast(unsigned short, (_Float16)b);
    return ha | (hb << 16);
}
__device__ __forceinline__ unsigned pkrtz_(float a, float b) {
    return __builtin_bit_cast(unsigned, __builtin_amdgcn_cvt_pkrtz(a, b));
}
__device__ __forceinline__ float flo_(float a) {   // a - f16(a)
    return a - (float)((_Float16)a);
}
__device__ __forceinline__ float sigmoidf_(float x) {
    return __builtin_amdgcn_rcpf(1.0f + __expf(-x));
}
__device__ __forceinline__ float tanhf_(float x) {
    x = fminf(fmaxf(x, -15.0f), 15.0f);
    float e = __expf(2.0f * x);
    return (e - 1.0f) * __builtin_amdgcn_rcpf(e + 1.0f);
}
#define MFMA16(a, b, c) __builtin_amdgcn_mfma_f32_16x16x32_f16((a), (b), (c), 0, 0, 0)

// lgkm-only barrier: does NOT drain vmcnt -> global prefetch regs survive
// across per-step barriers. Single asm stmt + "memory" clobber = compiler
// cannot move any memory op across it (rule #18-safe: no split waitcnt).
#define STEP_BARRIER() asm volatile("s_waitcnt lgkmcnt(0)\n\ts_barrier" ::: "memory")

// LDS strides (elements).
#define XST 40    // xh: per-(t,c) stride in f16 (80B, /16B = 5 odd)
#define HST 72    // hb: per-c stride in f16   (144B, /16B = 9 odd)
#define YST 65    // ya: per-(t,w) stride in f32

// R15 (rebench — round 3 broker timeout, never measured):
//  - x-path MFMAs + Bx read hoisted one step ahead (ping-pong f32x4 accs):
//    the serial chain now starts at the Bh ds_reads, h-MFMAs chain onto a
//    ready C (R14 chained Bx-read->x-MFMA->h-MFMAs all on-chain).
//  - __syncthreads -> raw lgkm-barrier (no vmcnt drain).
//  - next-chunk x/dt prefetched into registers once per chunk (outstanding
//    vmem across step barriers, legal with the raw barrier).
__global__ __launch_bounds__(256, 1) void brios_main(
    const float* __restrict__ x, const float* __restrict__ dt,
    const float* __restrict__ f_Wih, const float* __restrict__ f_Whh,
    const float* __restrict__ f_bih, const float* __restrict__ f_bhh,
    const float* __restrict__ f_gamma, const float* __restrict__ f_Wout,
    const float* __restrict__ f_bout,
    const float* __restrict__ b_Wih, const float* __restrict__ b_Whh,
    const float* __restrict__ b_bih, const float* __restrict__ b_bhh,
    const float* __restrict__ b_gamma, const float* __restrict__ b_Wout,
    const float* __restrict__ b_bout,
    float* __restrict__ out)
{
    const int tid  = threadIdx.x;
    const int w    = tid >> 6;          // wave id 0..3
    const int lane = tid & 63;
    const int lr   = lane & 15;         // A row-in-tile / B,C column (batch)
    const int lg   = lane >> 4;         // k-octet group / C row-quad

    const int dir = blockIdx.x >> 5;    // 2 dirs x 32 groups
    const int bg  = blockIdx.x & 31;

    const float* Wih  = dir ? b_Wih  : f_Wih;
    const float* Whh  = dir ? b_Whh  : f_Whh;
    const float* bih  = dir ? b_bih  : f_bih;
    const float* bhh  = dir ? b_bhh  : f_bhh;
    const float* Wout = dir ? b_Wout : f_Wout;
    float gam = dir ? b_gamma[0] : f_gamma[0];
    gam = fminf(fmaxf(gam, 1e-4f), 10.0f);
    const float bo = dir ? b_bout[0] : f_bout[0];

    const int tS = tid >> 4, cS = tid & 15;            // staging coords
    const size_t bB = (size_t)bg * NB;                 // first batch of block

    // ---- chunk x/dt register prefetch (double-buffered across chunks)
    float4 pv0, pv1, pv2, pv3;
    float pdt = 0.0f, pdt2 = 0.0f;
    auto PREF = [&](int cc) __attribute__((always_inline)) {
        int s  = cc * CH + tS;
        int tt = dir ? (LL - 1 - s) : s;
        const float* xp = x + ((bB + cS) * LL + tt) * DD;
        pv0 = ((const float4*)xp)[0];
        pv1 = ((const float4*)xp)[1];
        pv2 = ((const float4*)xp)[2];
        pv3 = ((const float4*)xp)[3];
        pdt = dt[(bB + cS) * LL + tt];
        int s2 = cc * CH + CH;
        if (tid < NB && s2 < LL) {
            int t2 = dir ? (LL - 1 - s2) : s2;
            pdt2 = dt[(bB + tid) * LL + t2];
        }
    };
    PREF(0);   // issue before the weight-load phase; overlaps it

    // ---- A fragments (weights), f16. Layout: row = lr, k = 8*lg + j.
    const int arow = 16 * w + lr;       // row within each 64-row gate block
    half8 AhR[2], AhZ[2], AhN[2];
#pragma unroll
    for (int kt = 0; kt < 2; ++kt)
#pragma unroll
        for (int j = 0; j < 8; ++j) {
            int k = kt * 32 + lg * 8 + j;
            AhR[kt][j] = (_Float16)Whh[(size_t)(arow      ) * HH + k];
            AhZ[kt][j] = (_Float16)Whh[(size_t)(arow +  64) * HH + k];
            AhN[kt][j] = (_Float16)Whh[(size_t)(arow + 128) * HH + k];
        }
    // x-side: K=32 where k<16 multiplies x_hi, k>=16 multiplies x_lo with the
    // SAME Wih column -> W*(x_hi + x_lo) = W*x at ~f32 input precision.
    half8 AxR, AxZ, AxN;
#pragma unroll
    for (int j = 0; j < 8; ++j) {
        int k = (lg * 8 + j) & 15;
        AxR[j] = (_Float16)Wih[(size_t)(arow      ) * DD + k];
        AxZ[j] = (_Float16)Wih[(size_t)(arow +  64) * DD + k];
        AxN[j] = (_Float16)Wih[(size_t)(arow + 128) * DD + k];
    }

    // ---- per-lane bias / wout (C layout: col=lr, rows rrow..rrow+3)
    const int rrow = 16 * w + 4 * lg;
    f32x4 bR, bZ, bNX, bNH;
    float wo4[4];
#pragma unroll
    for (int j = 0; j < 4; ++j) {
        bR[j]  = bih[rrow + j]       + bhh[rrow + j];
        bZ[j]  = bih[64 + rrow + j]  + bhh[64 + rrow + j];
        bNX[j] = bih[128 + rrow + j];
        bNH[j] = bhh[128 + rrow + j];
        wo4[j] = Wout[rrow + j];
    }

    __shared__ alignas(16) _Float16 xh[CH][NB][XST];   // x B-frags (hi|lo), per t
    __shared__ alignas(16) _Float16 hb[2][NB][HST];    // hbar B-frags, dbuf
    __shared__ float dcy[CH + 1][NB];                  // decay per (t, batch)
    __shared__ float ya[CH][4][YST];                   // per-wave y partials

    // ---- init hbar(0) = 0 (every wave covers its own rows; visibility is
    //      gated by the first staging barrier)
    *(uint2*)&hb[0][lr][rrow] = make_uint2(0u, 0u);
    f32x4 hb4 = {0.f, 0.f, 0.f, 0.f};                  // own rows' hbar, f32

    float* yd = out + (size_t)(1 + dir) * (BB * LL);

    // x-gate accumulators, ping-pong (computed one step ahead)
    f32x4 xrA, xzA, xnA, xrB, xzB, xnB;

    // one GRU step. Consumes x-accs (xrC,xzC,xnC) for step lt; prefetches
    // Bx(lt+1) and issues its x-MFMAs into (xrN,xzN,xnN) — off the chain.
    auto STEP = [&](int lt,
                    f32x4& xrC, f32x4& xzC, f32x4& xnC,
                    f32x4& xrN, f32x4& xzN, f32x4& xnN)
                    __attribute__((always_inline)) {
        const int rb = lt & 1;
        // chain-critical reads first
        half8 Bh0 = *(const half8*)&hb[rb][lr][lg * 8];
        half8 Bh1 = *(const half8*)&hb[rb][lr][32 + lg * 8];
        float dnx = dcy[lt + 1][lr];
        int nx = (lt + 1 < CH) ? lt + 1 : lt;          // clamp (last is dummy)
        half8 BxN = *(const half8*)&xh[nx][lr][lg * 8];

        // h-MFMAs chained on the prefetched x-accs (R14 order: bias->x->h0->h1)
        f32x4 aR  = MFMA16(AhR[0], Bh0, xrC);
        f32x4 aNH = MFMA16(AhN[0], Bh0, bNH);
        f32x4 aZ  = MFMA16(AhZ[0], Bh0, xzC);
        aR  = MFMA16(AhR[1], Bh1, aR);
        aNH = MFMA16(AhN[1], Bh1, aNH);
        aZ  = MFMA16(AhZ[1], Bh1, aZ);

        // next step's x-MFMAs (independent regs, consumed next step)
        xrN = MFMA16(AxR, BxN, bR);
        xzN = MFMA16(AxZ, BxN, bZ);
        xnN = MFMA16(AxN, BxN, bNX);

        f32x4 hnew, hbn;
#pragma unroll
        for (int j = 0; j < 4; ++j) {
            float r  = sigmoidf_(aR[j]);
            float zz = sigmoidf_(aZ[j]);
            float n  = tanhf_(xnC[j] + r * aNH[j]);
            hnew[j] = n + zz * (hb4[j] - n);
            hbn[j]  = hnew[j] * dnx;
        }

        // critical tail: pack + write next hbar
        unsigned p0 = pkrtz_(hbn[0], hbn[1]);
        unsigned p1 = pkrtz_(hbn[2], hbn[3]);
        *(uint2*)&hb[rb ^ 1][lr][rrow] = make_uint2(p0, p1);
        hb4 = hbn;

        // y partial (off-chain)
        float sy = wo4[0] * hnew[0] + wo4[1] * hnew[1]
                 + wo4[2] * hnew[2] + wo4[3] * hnew[3];
        ya[lt][w][lane] = sy;

        STEP_BARRIER();
    };

#pragma unroll 1
    for (int c0 = 0; c0 < LL / CH; ++c0) {
        const int s0 = c0 * CH;

        // ---- stage x (hi/lo f16) and decay from the prefetched registers
        {
            float vv[16];
            *(float4*)(vv + 0)  = pv0;
            *(float4*)(vv + 4)  = pv1;
            *(float4*)(vv + 8)  = pv2;
            *(float4*)(vv + 12) = pv3;
            unsigned uh[8], ul[8];
#pragma unroll
            for (int d = 0; d < 8; ++d) {
                float a = vv[2 * d], b2 = vv[2 * d + 1];
                uh[d] = pk2_(a, b2);
                ul[d] = pk2_(flo_(a), flo_(b2));
            }
            *(uint4*)&xh[tS][cS][0]  = make_uint4(uh[0], uh[1], uh[2], uh[3]);
            *(uint4*)&xh[tS][cS][8]  = make_uint4(uh[4], uh[5], uh[6], uh[7]);
            *(uint4*)&xh[tS][cS][16] = make_uint4(ul[0], ul[1], ul[2], ul[3]);
            *(uint4*)&xh[tS][cS][24] = make_uint4(ul[4], ul[5], ul[6], ul[7]);

            float dv = fminf(fmaxf(pdt, 0.0f), 1e6f);
            dcy[tS][cS] = __expf(-gam * dv);
            if (tid < NB) {                    // one-past-chunk decay
                float d = 0.0f;
                if (s0 + CH < LL) {
                    float dv2 = fminf(fmaxf(pdt2, 0.0f), 1e6f);
                    d = __expf(-gam * dv2);
                }
                dcy[CH][tid] = d;
            }
        }
        STEP_BARRIER();

        // ---- issue NEXT chunk's global loads; stay outstanding across the
        //      step barriers (lgkm-only), consumed at next chunk's staging
        if (c0 + 1 < LL / CH) PREF(c0 + 1);

        // ---- preload step 0's x-gates
        {
            half8 Bx0 = *(const half8*)&xh[0][lr][lg * 8];
            xrA = MFMA16(AxR, Bx0, bR);
            xzA = MFMA16(AxZ, Bx0, bZ);
            xnA = MFMA16(AxN, Bx0, bNX);
        }

        // ---- recurrent steps (manual 2-unroll, ping-pong x-accs)
#pragma unroll 1
        for (int lt = 0; lt < CH; lt += 2) {
            STEP(lt,     xrA, xzA, xnA, xrB, xzB, xnB);
            STEP(lt + 1, xrB, xzB, xnB, xrA, xzA, xnA);
        }

        // ---- y: reduce 16 partials per (t, batch), store
        {
            int lt2 = tid & 15, c2 = tid >> 4;
            float sacc = 0.0f;
#pragma unroll
            for (int w2 = 0; w2 < 4; ++w2)
#pragma unroll
                for (int g = 0; g < 4; ++g)
                    sacc += ya[lt2][w2][g * 16 + c2];
            int s  = s0 + lt2;
            int tt = dir ? (LL - 1 - s) : s;
            yd[(bB + c2) * LL + tt] = sacc + bo;
        }
        // no trailing barrier: next staging writes xh/dcy (not read anymore),
        // its own barrier gates the next chunk's reads; ya re-writes are
        // gated by that same barrier.
    }
}

__global__ __launch_bounds__(256) void brios_avg(float* __restrict__ out)
{
    int i = blockIdx.x * blockDim.x + threadIdx.x;
    const int n4 = (BB * LL) / 4;
    if (i < n4) {
        const float4* yf = (const float4*)(out + (size_t)BB * LL);
        const float4* yb = (const float4*)(out + (size_t)2 * BB * LL);
        float4 a = yf[i], b2 = yb[i];
        float4 r;
        r.x = 0.5f * (a.x + b2.x);
        r.y = 0.5f * (a.y + b2.y);
        r.z = 0.5f * (a.z + b2.z);
        r.w = 0.5f * (a.w + b2.w);
        ((float4*)out)[i] = r;
    }
}

extern "C" void kernel_launch(void* const* d_in, const int* in_sizes, int n_in,
                              void* d_out, int out_size, void* d_ws, size_t ws_size,
                              hipStream_t stream) {
    const float* x       = (const float*)d_in[0];
    const float* dt      = (const float*)d_in[1];
    const float* f_Wih   = (const float*)d_in[2];
    const float* f_Whh   = (const float*)d_in[3];
    const float* f_bih   = (const float*)d_in[4];
    const float* f_bhh   = (const float*)d_in[5];
    const float* f_gamma = (const float*)d_in[6];
    const float* f_Wout  = (const float*)d_in[7];
    const float* f_bout  = (const float*)d_in[8];
    const float* b_Wih   = (const float*)d_in[9];
    const float* b_Whh   = (const float*)d_in[10];
    const float* b_bih   = (const float*)d_in[11];
    const float* b_bhh   = (const float*)d_in[12];
    const float* b_gamma = (const float*)d_in[13];
    const float* b_Wout  = (const float*)d_in[14];
    const float* b_bout  = (const float*)d_in[15];
    float* out = (float*)d_out;

    brios_main<<<64, 256, 0, stream>>>(x, dt,
        f_Wih, f_Whh, f_bih, f_bhh, f_gamma, f_Wout, f_bout,
        b_Wih, b_Whh, b_bih, b_bhh, b_gamma, b_Wout, b_bout, out);

    const int n4 = (BB * LL) / 4;
    brios_avg<<<(n4 + 255) / 256, 256, 0, stream>>>(out);
}